// Round 1
// 238.618 us; speedup vs baseline: 2.0303x; 2.0303x over previous
//
#include <hip/hip_runtime.h>
#include <stdint.h>

typedef unsigned short u16;
typedef unsigned int   u32;

#define EPSF  1e-7f
#define MINN  1e-15f

// problem constants: n=8192, t=16, d=64
#define CPR  524288      // cols per big row (n*d)
#define NE   136         // number of (m,nn) pairs
#define WSFLAG 960       // ws[960] = 1.0 if float32 inputs, 0.0 if bf16
#define QS   68          // qv/kv row stride (floats)

__device__ __forceinline__ float bf2f(u16 u){ u32 x = ((u32)u)<<16; return __uint_as_float(x); }
__device__ __forceinline__ float ldv(const void* p, size_t i, int f32m){
    return f32m ? ((const float*)p)[i] : bf2f(((const u16*)p)[i]);
}
__device__ __forceinline__ float arcosh_f(float x){
    return logf(x + sqrtf(fmaxf(x*x - 1.0f, EPSF)));
}
__device__ __forceinline__ float clampf(float v, float lim){
    return fmaxf(fminf(v, lim), -lim);
}
__device__ __forceinline__ float red16(float v){
    v += __shfl_xor(v,1); v += __shfl_xor(v,2);
    v += __shfl_xor(v,4); v += __shfl_xor(v,8);
    return v;
}

// ---------------------------------------------------------------------------
// Kernel 0: dtype detect (f32 vs bf16) via range test on big_h[i,0,0].
// ---------------------------------------------------------------------------
__global__ void detect_k(const void* __restrict__ Hv, float* __restrict__ ws){
    if(threadIdx.x==0){
        const float* Hf = (const float*)Hv;
        int ok = 1;
        for(int i=0;i<16;i++){
            float v = Hf[(size_t)i*1024];
            if(!(v > 0.9f && v < 1000.f)) ok = 0;
        }
        ws[WSFLAG] = ok ? 1.f : 0.f;
    }
}

// ---------------------------------------------------------------------------
// Kernel 1: Gram matrix of the 16 big rows over ALL columns (col-0 product
// subtracted in finalize). G[p] for pairs (s<=s2), row-major pair order.
//
// Restructured: 4 pair-groups x 34 pairs. Each group re-reads H (H = 33.5 MB,
// fully L2/L3-resident, so re-reads are cheap) but keeps the per-thread
// accumulator footprint at 34 regs instead of 136 -> no AGPR shuttling,
// ~110 VGPRs, 4 waves/SIMD instead of 1. Grid 1024 blocks (4 groups x 256).
// Pair decode is fully compile-time (templated group + unrolled induction
// counter) so the row array is never dynamically indexed.
// Reduction: 64-lane shuffle reduce -> 1 LDS atomic per wave per pair ->
// 34 global atomics per block (kills the old 64-way same-address LDS storm).
// ---------------------------------------------------------------------------
template<int G>
__device__ __forceinline__ void gram_grp(const void* __restrict__ Hv,
                                         float* __restrict__ ws,
                                         int f32m, int tid, int nthr){
    constexpr int P0  = 34*G;
    constexpr int NC4 = 131072;     // groups of 4 float-columns per row
    float acc[34];
#pragma unroll
    for(int j=0;j<34;j++) acc[j]=0.f;

    if(f32m){
        const float4* H4 = (const float4*)Hv;
        for(int c = tid; c < NC4; c += nthr){
            float4 hx[16];
#pragma unroll
            for(int s=0;s<16;s++) hx[s] = H4[(size_t)s*NC4 + c];
            int p = 0;
#pragma unroll
            for(int s=0;s<16;s++){
#pragma unroll
                for(int s2=s;s2<16;s2++){
                    if(p >= P0 && p < P0+34){
                        acc[p-P0] += hx[s].x*hx[s2].x + hx[s].y*hx[s2].y
                                   + hx[s].z*hx[s2].z + hx[s].w*hx[s2].w;
                    }
                    p++;
                }
            }
        }
    } else {
        const ushort4* Hu4 = (const ushort4*)Hv;
        for(int c = tid; c < NC4; c += nthr){
            float4 hx[16];
#pragma unroll
            for(int s=0;s<16;s++){
                ushort4 u4 = Hu4[(size_t)s*NC4 + c];
                hx[s] = make_float4(bf2f(u4.x), bf2f(u4.y), bf2f(u4.z), bf2f(u4.w));
            }
            int p = 0;
#pragma unroll
            for(int s=0;s<16;s++){
#pragma unroll
                for(int s2=s;s2<16;s2++){
                    if(p >= P0 && p < P0+34){
                        acc[p-P0] += hx[s].x*hx[s2].x + hx[s].y*hx[s2].y
                                   + hx[s].z*hx[s2].z + hx[s].w*hx[s2].w;
                    }
                    p++;
                }
            }
        }
    }

    // 64-lane butterfly reduce each accumulator
#pragma unroll
    for(int j=0;j<34;j++){
        float v = acc[j];
        v += __shfl_xor(v,1);  v += __shfl_xor(v,2);  v += __shfl_xor(v,4);
        v += __shfl_xor(v,8);  v += __shfl_xor(v,16); v += __shfl_xor(v,32);
        acc[j] = v;
    }
    __shared__ float red[34];
    if(threadIdx.x < 34) red[threadIdx.x] = 0.f;
    __syncthreads();
    if((threadIdx.x & 63) == 0){
#pragma unroll
        for(int j=0;j<34;j++) atomicAdd(&red[j], acc[j]);
    }
    __syncthreads();
    if(threadIdx.x < 34) atomicAdd(&ws[P0 + threadIdx.x], red[threadIdx.x]);
}

__global__ __launch_bounds__(256,4) void gram_k(const void* __restrict__ Hv, float* __restrict__ ws){
    const int f32m = (ws[WSFLAG] != 0.f);
    const int g    = blockIdx.x >> 8;                    // pair group 0..3
    const int tid  = (blockIdx.x & 255)*256 + threadIdx.x;
    const int nthr = 256*256;
    switch(g){
        case 0: gram_grp<0>(Hv, ws, f32m, tid, nthr); break;
        case 1: gram_grp<1>(Hv, ws, f32m, tid, nthr); break;
        case 2: gram_grp<2>(Hv, ws, f32m, tid, nthr); break;
        default: gram_grp<3>(Hv, ws, f32m, tid, nthr); break;
    }
}

// ---------------------------------------------------------------------------
// Kernel 2: finalize scalars.
// ws layout (floats): [0..135] G, [256..511] wqp, [512..767] wkp,
// [768..783] scaleQ, [784..799] scaleK, [800..815] coshQ, [816..831] coshK,
// [832..895] uq, [896..959] uk, [960] dtype flag
// ---------------------------------------------------------------------------
__global__ void fin_k(const void* __restrict__ Hv, const void* __restrict__ wq, const void* __restrict__ wk,
                      const void* __restrict__ bq, const void* __restrict__ bk, const void* __restrict__ cc,
                      float* __restrict__ ws){
    __shared__ float Gy[16][16], alpha[16], h0s[16], wqp[16][16], wkp[16][16], aus[2];
    int tid = threadIdx.x;
    const int f32m = (ws[WSFLAG] != 0.f);
    float cv = fmaxf(ldv(cc,0,f32m), 1e-20f);
    float K = 1.f/cv, sqK = sqrtf(K);
    if(tid<16) h0s[tid] = ldv(Hv, (size_t)tid*CPR, f32m);
    __syncthreads();
    if(tid<NE){
        int s=0, rem=tid;
        while(rem >= 16 - s){ rem -= 16 - s; s++; }
        int s2 = s + rem;
        float g = ws[tid] - h0s[s]*h0s[s2];
        Gy[s][s2] = g; Gy[s2][s] = g;
    }
    __syncthreads();
    if(tid<16){
        float ny = fmaxf(sqrtf(fmaxf(Gy[tid][tid],0.f)), MINN);
        float th = fmaxf(h0s[tid]/sqK, 1.0f+EPSF);
        alpha[tid] = sqK*arcosh_f(th)/ny;
    }
    __syncthreads();
    {
        int r = tid>>4, s = tid&15;
        float aq = ldv(wq,tid,f32m)*alpha[s];
        float ak = ldv(wk,tid,f32m)*alpha[s];
        wqp[r][s] = aq; wkp[r][s] = ak;
        ws[256+tid] = aq; ws[512+tid] = ak;
    }
    if(tid==0){
        float b0 = ldv(bq,0,f32m); float sn=0.f;
        for(int j=1;j<64;j++){ float v=ldv(bq,j,f32m); sn += v*v; }
        float nb = fmaxf(sqrtf(sn), MINN);
        float th = fmaxf(b0/sqK, 1.0f+EPSF);
        aus[0] = sqK*arcosh_f(th)/nb;
        b0 = ldv(bk,0,f32m); sn=0.f;
        for(int j=1;j<64;j++){ float v=ldv(bk,j,f32m); sn += v*v; }
        nb = fmaxf(sqrtf(sn), MINN);
        th = fmaxf(b0/sqK, 1.0f+EPSF);
        aus[1] = sqK*arcosh_f(th)/nb;
    }
    __syncthreads();
    if(tid<32){
        int r = tid&15;
        float qf = 0.f;
        if(tid<16){
            for(int s=0;s<16;s++){ float ww = wqp[r][s];
                for(int s2=0;s2<16;s2++) qf += ww*wqp[r][s2]*Gy[s][s2]; }
        } else {
            for(int s=0;s<16;s++){ float ww = wkp[r][s];
                for(int s2=0;s2<16;s2++) qf += ww*wkp[r][s2]*Gy[s][s2]; }
        }
        float xn = fmaxf(sqrtf(fmaxf(qf,0.f)), MINN);
        float thc = fminf(xn/sqK, 80.f);
        ws[768 + tid] = clampf(sqK*sinhf(thc)/xn, 1e18f);   // scaleQ / scaleK
        ws[800 + tid] = clampf(sqK*coshf(thc),    1e18f);   // coshQ  / coshK
    }
    if(tid<64){
        ws[832+tid] = (tid==0)?0.f : clampf(aus[0]*ldv(bq,tid,f32m), 1e18f);
        ws[896+tid] = (tid==0)?0.f : clampf(aus[1]*ldv(bk,tid,f32m), 1e18f);
    }
}

// ---------------------------------------------------------------------------
// Kernel 3: fused transform + attention. One block per i0 (512 blocks);
// iteration r handles sample i = 512*r + i0.  FLOAT32 OUTPUT.
// ---------------------------------------------------------------------------
__global__ __launch_bounds__(256) void main_k(const void* __restrict__ Hv, const int* __restrict__ tidx,
        const void* __restrict__ mask, const void* __restrict__ aa, const void* __restrict__ cc,
        const float* __restrict__ ws, float* __restrict__ out){
    __shared__ __attribute__((aligned(16))) float vrow[1024];
    __shared__ __attribute__((aligned(16))) float qv[16*QS];
    __shared__ __attribute__((aligned(16))) float kv[16*QS];
    __shared__ float wqp[256], wkp[256], scQ[16], scK[16], chQ[16], chK[16], uq[64], uk[64];
    __shared__ float ssum[16], Cm[256], lamb[16], invv[16];
    __shared__ int   tmv[NE], tnv[NE];
    __shared__ float maskv[NE];

    const int tid = threadIdx.x;
    const int i0  = blockIdx.x;
    const int row = tid>>4, l = tid&15;
    const int f32m = (ws[WSFLAG] != 0.f);
    const float av = ldv(aa,0,f32m);
    const float cv = fmaxf(ldv(cc,0,f32m), 1e-20f);
    const float K = 1.f/cv, sqK = sqrtf(K);
    const int i64m = (tidx[1] != 1);   // int64 time_index read as int32 pairs

    wqp[tid] = ws[256+tid]; wkp[tid] = ws[512+tid];
    if(tid<16){ scQ[tid]=ws[768+tid]; scK[tid]=ws[784+tid]; chQ[tid]=ws[800+tid]; chK[tid]=ws[816+tid]; }
    if(tid<64){ uq[tid]=ws[832+tid]; uk[tid]=ws[896+tid]; }
    if(tid<NE){
        if(i64m){ tmv[tid]=tidx[2*tid]&15; tnv[tid]=tidx[2*NE+2*tid]&15; }
        else    { tmv[tid]=tidx[tid]&15;   tnv[tid]=tidx[NE+tid]&15; }
        maskv[tid]=ldv(mask,tid,f32m);
    }
    __syncthreads();

    const float* Hf = (const float*)Hv;
    const u16*   Hu = (const u16*)Hv;
    const int c0 = tid*4;

    for(int r=0;r<16;r++){
        // --- A: M = W' * tile (global reads), scale, special col-0 ---
        {
            float aq0=0,aq1=0,aq2=0,aq3=0, ak0=0,ak1=0,ak2=0,ak3=0;
#pragma unroll
            for(int s=0;s<16;s++){
                float b0,b1,b2,b3;
                if(f32m){
                    float4 v = *(const float4*)(Hf + ((size_t)(512*s + i0))*1024 + c0);
                    b0=v.x; b1=v.y; b2=v.z; b3=v.w;
                } else {
                    ushort4 u4 = *(const ushort4*)(Hu + ((size_t)(512*s + i0))*1024 + c0);
                    b0=bf2f(u4.x); b1=bf2f(u4.y); b2=bf2f(u4.z); b3=bf2f(u4.w);
                }
                float wq_ = wqp[r*16+s], wk_ = wkp[r*16+s];
                aq0 += wq_*b0; aq1 += wq_*b1; aq2 += wq_*b2; aq3 += wq_*b3;
                ak0 += wk_*b0; ak1 += wk_*b1; ak2 += wk_*b2; ak3 += wk_*b3;
            }
            float sq_ = scQ[r], sk_ = scK[r];
            float q0 = clampf(sq_*aq0,1e18f), q1=clampf(sq_*aq1,1e18f),
                  q2 = clampf(sq_*aq2,1e18f), q3=clampf(sq_*aq3,1e18f);
            float k0 = clampf(sk_*ak0,1e18f), k1=clampf(sk_*ak1,1e18f),
                  k2 = clampf(sk_*ak2,1e18f), k3=clampf(sk_*ak3,1e18f);
            if(i0==0 && tid==0){ q0 = chQ[r]; k0 = chK[r]; }
            *(float4*)(qv + row*QS + l*4) = make_float4(q0,q1,q2,q3);
            *(float4*)(kv + row*QS + l*4) = make_float4(k0,k1,k2,k3);
        }

        // --- C1: v row, per-row Lorenz stats; zero ssum/Cm ---
        {
            if(f32m){
                *(float4*)(vrow + c0) = *(const float4*)(Hf + ((size_t)(512*r + i0))*1024 + c0);
            } else {
                ushort4 u4 = *(const ushort4*)(Hu + ((size_t)(512*r + i0))*1024 + c0);
                vrow[c0+0]=bf2f(u4.x); vrow[c0+1]=bf2f(u4.y);
                vrow[c0+2]=bf2f(u4.z); vrow[c0+3]=bf2f(u4.w);
            }
            float x0v = vrow[row*64];
            float inv0 = 1.f/((fabsf(x0v)>1e-20f)? x0v : 1e-20f);
            float sv = 0.f;
#pragma unroll
            for(int m=0;m<4;m++){
                int kp = l + 16*m;
                if(kp < 63){ float vi = vrow[row*64 + 1 + kp]*inv0; sv += vi*vi; }
            }
            sv = red16(sv);
            if(l==0){ lamb[row] = 1.f/sqrtf(1.f - fminf(sv, 0.9f)); invv[row] = inv0; }
            if(tid<16) ssum[tid]=0.f;
            Cm[tid]=0.f;
        }

        // --- M: mobius_add(+proj) on q and k rows, in-wave ---
        {
            float xq[4], xk[4];
            float syq=0,suq=0,syk=0,suk=0;
#pragma unroll
            for(int m=0;m<4;m++){
                int k = l+16*m;
                xq[m]=qv[row*QS+k]; xk[m]=kv[row*QS+k];
                if(k>0){ syq+=xq[m]*xq[m]; suq+=xq[m]*uq[k];
                         syk+=xk[m]*xk[m]; suk+=xk[m]*uk[k]; }
            }
            syq=red16(syq); suq=red16(suq); syk=red16(syk); suk=red16(suk);
            float x0q=qv[row*QS], x0k=kv[row*QS];
            float xnq=fmaxf(sqrtf(fmaxf(syq,0.f)),MINN);
            float xnk=fmaxf(sqrtf(fmaxf(syk,0.f)),MINN);
            float alq=clampf(suq/(xnq*sqK),1e12f);
            float alk=clampf(suk/(xnk*sqK),1e12f);
            float cfq=clampf(alq*(sqK-x0q)/xnq,1e12f);
            float cfk=clampf(alk*(sqK-x0k)/xnk,1e12f);
            float wq4[4], wk4[4];
            float uxq=0,swq=0,uxk=0,swk=0;
#pragma unroll
            for(int m=0;m<4;m++){
                int k=l+16*m;
                if(k>0){
                    wq4[m]=clampf(uq[k]-cfq*xq[m],1e15f); uxq+=xq[m]*wq4[m]; swq+=wq4[m]*wq4[m];
                    wk4[m]=clampf(uk[k]-cfk*xk[m],1e15f); uxk+=xk[m]*wk4[m]; swk+=wk4[m]*wk4[m];
                } else { wq4[m]=0.f; wk4[m]=0.f; }
            }
            uxq=red16(uxq); swq=red16(swq); uxk=red16(uxk); swk=red16(swk);
            float V0q=uxq/fmaxf(x0q,EPSF);
            float V0k=uxk/fmaxf(x0k,EPSF);
            float mnq=sqrtf(fmaxf(swq-V0q*V0q,EPSF));
            float mnk=sqrtf(fmaxf(swk-V0k*V0k,EPSF));
            float thq=fminf(fmaxf(fminf(mnq,1e6f)/sqK,MINN),20.f);
            float thk=fminf(fmaxf(fminf(mnk,1e6f)/sqK,MINN),20.f);
            float chq=coshf(thq), stq=sinhf(thq)/thq;
            float chk=coshf(thk), stk=sinhf(thk)/thk;
            float zq4[4], zk4[4];
            float szq=0,szk=0;
#pragma unroll
            for(int m=0;m<4;m++){
                int k=l+16*m;
                if(k>0){
                    zq4[m]=clampf(chq*xq[m]+stq*wq4[m],1e15f); szq+=zq4[m]*zq4[m];
                    zk4[m]=clampf(chk*xk[m]+stk*wk4[m],1e15f); szk+=zk4[m]*zk4[m];
                } else { zq4[m]=0.f; zk4[m]=0.f; }
            }
            szq=red16(szq); szk=red16(szk);
            float fq = sqrtf(fmaxf(K+szq,EPSF));
            float fk = sqrtf(fmaxf(K+szk,EPSF));
#pragma unroll
            for(int m=0;m<4;m++){
                int k=l+16*m;
                qv[row*QS+k] = (k==0)? fq : zq4[m];
                kv[row*QS+k] = (k==0)? fk : zk4[m];
            }
        }
        __syncthreads();   // qv/kv/lamb/invv/ssum/Cm ready

        // --- C2: scores; scatter s_sum; stash sval in Cm ---
        if(tid<NE){
            int m = tmv[tid], nn = tnv[tid];
            const float4* qp = (const float4*)(qv + m*QS);
            const float4* kp = (const float4*)(kv + nn*QS);
            float dot = 0.f;
#pragma unroll
            for(int t4=0;t4<16;t4++){
                float4 q4 = qp[t4], k4 = kp[t4];
                dot += q4.x*k4.x + q4.y*k4.y + q4.z*k4.z + q4.w*k4.w;
            }
            float mdot = dot - 2.f*qv[m*QS]*kv[nn*QS];
            float th = fmaxf(-mdot/K, 1.0f+EPSF);
            float ac = arcosh_f(th);
            float sqd = fminf(K*ac*ac, 50.f);
            float sval = expf(fminf(-av*sqd - cv + maskv[tid], 80.f));
            Cm[m*16+nn] = sval;
            atomicAdd(&ssum[m], sval);
        }
        __syncthreads();

        // --- C3: Cm[m][nn] = lamb[nn] * s / s_sum[nn] ---
        if(tid<NE){
            int m = tmv[tid], nn = tnv[tid];
            Cm[m*16+nn] = lamb[nn]*Cm[m*16+nn]/fmaxf(ssum[nn],1e-37f);
        }
        __syncthreads();

        // --- D: weighted Klein average + k2h, FLOAT32 output ---
        {
            float cs[16]; float wsm = 0.f;
#pragma unroll
            for(int s=0;s<16;s++){
                float cmv = Cm[row*16+s];
                wsm += cmv;
                cs[s] = cmv*invv[s];
            }
            wsm = fmaxf(wsm, 1e-37f);
            float g4[4]; float sg=0.f;
#pragma unroll
            for(int m=0;m<4;m++){
                int kp = l+16*m;
                float num = 0.f;
#pragma unroll
                for(int s=0;s<16;s++) num += cs[s]*vrow[s*64 + 1 + kp];
                float gvv = (kp<63)? num/wsm : 0.f;
                g4[m]=gvv; sg += gvv*gvv;
            }
            sg = red16(sg);
            float inv = 1.f/sqrtf(1.f - fminf(sg, 0.999f));
            size_t base = ((size_t)(512*r + i0)*16 + row)*64;
            if(l==0) out[base] = inv;
#pragma unroll
            for(int m=0;m<4;m++){
                int kp=l+16*m;
                if(kp<63) out[base+1+kp] = g4[m]*inv;
            }
        }
        __syncthreads();   // protect vrow/qv/kv/Cm/ssum for next r
    }
}

extern "C" void kernel_launch(void* const* d_in, const int* in_sizes, int n_in,
                              void* d_out, int out_size, void* d_ws, size_t ws_size,
                              hipStream_t stream){
    const void* H    = d_in[0];
    const int* tidx  = (const int*)d_in[1];
    const void* mask = d_in[2];
    const void* wq   = d_in[3];
    const void* wk   = d_in[4];
    const void* bq   = d_in[5];
    const void* bk   = d_in[6];
    const void* aa   = d_in[7];
    const void* cc   = d_in[8];
    float* out = (float*)d_out;
    float* ws  = (float*)d_ws;

    hipMemsetAsync(ws, 0, NE*sizeof(float), stream);
    detect_k<<<1, 64, 0, stream>>>(H, ws);
    gram_k<<<1024,256,0,stream>>>(H, ws);
    fin_k <<<1,  256,0,stream>>>(H, wq, wk, bq, bk, cc, ws);
    main_k<<<512,256,0,stream>>>(H, tidx, mask, aa, cc, ws, out);
}